// Round 20
// baseline (49.979 us; speedup 1.0000x reference)
//
#include <hip/hip_runtime.h>
#include <math.h>

#define Bb 2
#define Tt 256
#define Ee 512
#define Hh 8
#define Dd 64
#define E3 1536
#define SCP 260

typedef float vfloat4 __attribute__((ext_vector_type(4)));
typedef short bf16x8 __attribute__((ext_vector_type(8)));
typedef float f32x4 __attribute__((ext_vector_type(4)));

__device__ inline float4 ntload4(const float* p) {
    vfloat4 v = __builtin_nontemporal_load((const vfloat4*)p);
    return make_float4(v.x, v.y, v.z, v.w);
}
template<int CTRL>
__device__ inline float dpp_addf(float v) {
    int x = __builtin_amdgcn_update_dpp(0, __float_as_int(v), CTRL, 0xF, 0xF, true);
    return v + __int_as_float(x);
}
__device__ inline float swz4_addf(float v) {
    int x = __builtin_amdgcn_ds_swizzle(__float_as_int(v), 0x101F);
    return v + __int_as_float(x);
}
__device__ inline unsigned short bf16rne(float f) {
    unsigned u = __float_as_uint(f);
    return (unsigned short)((u + 0x7FFFu + ((u >> 16) & 1u)) >> 16);
}
__device__ inline float bf16tof(unsigned short h) {
    return __uint_as_float(((unsigned)h) << 16);
}
__device__ inline bf16x8 ldb(const unsigned short* p) {
    return *(const bf16x8*)(const void*)p;
}
__device__ __forceinline__ void split8(const float* p, bf16x8& hi, bf16x8& lo) {
    const float4 a = *(const float4*)p, b = *(const float4*)(p + 4);
    float f[8] = {a.x, a.y, a.z, a.w, b.x, b.y, b.z, b.w};
    bf16x8 h, l;
    #pragma unroll
    for (int i = 0; i < 8; ++i) {
        const unsigned short hh = bf16rne(f[i]);
        h[i] = (short)hh;
        l[i] = (short)bf16rne(f[i] - bf16tof(hh));
    }
    hi = h; lo = l;
}
__device__ __forceinline__ void split8a(const float* f, bf16x8& hi, bf16x8& lo) {
    bf16x8 h, l;
    #pragma unroll
    for (int i = 0; i < 8; ++i) {
        const unsigned short hh = bf16rne(f[i]);
        h[i] = (short)hh;
        l[i] = (short)bf16rne(f[i] - bf16tof(hh));
    }
    hi = h; lo = l;
}
__device__ __forceinline__ f32x4 mfma3(f32x4 acc, bf16x8 ah, bf16x8 al,
                                       bf16x8 bh, bf16x8 bl) {
    acc = __builtin_amdgcn_mfma_f32_16x16x32_bf16(ah, bh, acc, 0, 0, 0);
    acc = __builtin_amdgcn_mfma_f32_16x16x32_bf16(al, bh, acc, 0, 0, 0);
    acc = __builtin_amdgcn_mfma_f32_16x16x32_bf16(ah, bl, acc, 0, 0, 0);
    return acc;
}

// Kernel 1 (r16-frozen): blocks 0..767 = qkv GEMM (split-K MFMA, B direct from
// row-major Wqkv); blocks 768..831 = transpose+split Wo.
__global__ __launch_bounds__(256) void mfma_qkv2(
    const float* __restrict__ x, const float* __restrict__ Wqkv,
    const float* __restrict__ bias, float* __restrict__ C,
    const float* __restrict__ Wo,
    unsigned short* __restrict__ Wohi, unsigned short* __restrict__ Wolo)
{
    const int bid = blockIdx.x;
    const int tid = threadIdx.x;

    if (bid >= 768) {
        __shared__ float tile[64][65];
        const int b2 = bid - 768;
        const int kt = b2 & 7, nt = b2 >> 3;
        const int rr = tid >> 2, cc = (tid & 3) * 16;
        #pragma unroll
        for (int j = 0; j < 4; ++j) {
            const float4 v = *(const float4*)&Wo[(size_t)(kt * 64 + rr) * 512 + nt * 64 + cc + j * 4];
            tile[rr][cc + j * 4 + 0] = v.x;
            tile[rr][cc + j * 4 + 1] = v.y;
            tile[rr][cc + j * 4 + 2] = v.z;
            tile[rr][cc + j * 4 + 3] = v.w;
        }
        __syncthreads();
        unsigned short hb[16], lb[16];
        #pragma unroll
        for (int j = 0; j < 16; ++j) {
            const float f = tile[cc + j][rr];
            const unsigned short h = bf16rne(f);
            hb[j] = h;
            lb[j] = bf16rne(f - bf16tof(h));
        }
        const size_t off = (size_t)(nt * 64 + rr) * 512 + kt * 64 + cc;
        *(uint4*)&Wohi[off]     = *(const uint4*)&hb[0];
        *(uint4*)&Wohi[off + 8] = *(const uint4*)&hb[8];
        *(uint4*)&Wolo[off]     = *(const uint4*)&lb[0];
        *(uint4*)&Wolo[off + 8] = *(const uint4*)&lb[8];
        return;
    }

    __shared__ f32x4 red[4][2][2][64];
    const int lane = tid & 63;
    const int wv   = tid >> 6;
    const int n0   = (bid % 48) * 32;
    const int m0   = (bid / 48) * 32;
    const int fr   = lane & 15;
    const int kg   = (lane >> 4) * 8;

    f32x4 acc00 = {0.f, 0.f, 0.f, 0.f}, acc01 = acc00, acc10 = acc00, acc11 = acc00;

    #pragma unroll
    for (int s = 0; s < 4; ++s) {
        const int k0 = wv * 128 + s * 32 + kg;
        bf16x8 ah0, al0, ah1, al1;
        split8(&x[(size_t)(m0 + fr) * 512 + k0], ah0, al0);
        split8(&x[(size_t)(m0 + 16 + fr) * 512 + k0], ah1, al1);
        float b0[8], b1[8];
        #pragma unroll
        for (int j = 0; j < 8; ++j) {
            b0[j] = Wqkv[(size_t)(k0 + j) * E3 + n0 + fr];
            b1[j] = Wqkv[(size_t)(k0 + j) * E3 + n0 + 16 + fr];
        }
        bf16x8 bh0, bl0, bh1, bl1;
        split8a(b0, bh0, bl0);
        split8a(b1, bh1, bl1);
        acc00 = mfma3(acc00, ah0, al0, bh0, bl0);
        acc01 = mfma3(acc01, ah0, al0, bh1, bl1);
        acc10 = mfma3(acc10, ah1, al1, bh0, bl0);
        acc11 = mfma3(acc11, ah1, al1, bh1, bl1);
    }
    red[wv][0][0][lane] = acc00;
    red[wv][0][1][lane] = acc01;
    red[wv][1][0][lane] = acc10;
    red[wv][1][1][lane] = acc11;
    __syncthreads();

    const int fi = wv >> 1, fj = wv & 1;
    f32x4 s0 = red[0][fi][fj][lane];
    const f32x4 s1 = red[1][fi][fj][lane];
    const f32x4 s2 = red[2][fi][fj][lane];
    const f32x4 s3 = red[3][fi][fj][lane];
    #pragma unroll
    for (int g = 0; g < 4; ++g) s0[g] = (s0[g] + s1[g]) + (s2[g] + s3[g]);
    const int dr = (lane >> 4) * 4, dc = lane & 15;
    const float bs = bias[n0 + fj * 16 + dc];
    #pragma unroll
    for (int g = 0; g < 4; ++g)
        C[(size_t)(m0 + fi * 16 + dr + g) * E3 + n0 + fj * 16 + dc] = s0[g] + bs;
}

// out = oa @ Wo^T + bo. NEW: 16x16 tile per block, grid 32x32 = 1024 blocks
// -> 4 blocks/CU (4 waves/SIMD) vs old 256 blocks (1 wave/SIMD). Split-K-4:
// wave wv owns k in [wv*128, wv*128+128). 1 fragment/wave, LDS reduce.
__global__ __launch_bounds__(256) void mfma_proj16(
    const unsigned short* __restrict__ Ahi, const unsigned short* __restrict__ Alo,
    const unsigned short* __restrict__ Bhi, const unsigned short* __restrict__ Blo,
    const float* __restrict__ bias, float* __restrict__ C, int M, int N)
{
    __shared__ f32x4 red[4][64];
    const int lane = threadIdx.x & 63;
    const int wv   = threadIdx.x >> 6;
    const int m0   = blockIdx.y * 16;
    const int n0   = blockIdx.x * 16;
    const int fr   = lane & 15;
    const int kg   = (lane >> 4) * 8;

    f32x4 acc = {0.f, 0.f, 0.f, 0.f};

    #pragma unroll
    for (int s = 0; s < 4; ++s) {
        const int k0 = wv * 128 + s * 32 + kg;
        const bf16x8 ah = ldb(Ahi + (size_t)(m0 + fr) * 512 + k0);
        const bf16x8 al = ldb(Alo + (size_t)(m0 + fr) * 512 + k0);
        const bf16x8 bh = ldb(Bhi + (size_t)(n0 + fr) * 512 + k0);
        const bf16x8 bl = ldb(Blo + (size_t)(n0 + fr) * 512 + k0);
        acc = mfma3(acc, ah, al, bh, bl);
    }
    red[wv][lane] = acc;
    __syncthreads();

    if (wv == 0) {
        f32x4 t = red[0][lane];
        #pragma unroll
        for (int r = 1; r < 4; ++r) {
            const f32x4 u = red[r][lane];
            #pragma unroll
            for (int g = 0; g < 4; ++g) t[g] += u[g];
        }
        const int dr = (lane >> 4) * 4, dc = lane & 15;
        const float bs = bias[n0 + dc];
        #pragma unroll
        for (int g = 0; g < 4; ++g)
            C[(size_t)(m0 + dr + g) * N + n0 + dc] = t[g] + bs;
    }
}

// attn (frozen since r13; ~8.8us, at its mask-HBM + v-L2 structural floor)
__global__ __launch_bounds__(512, 2) void attn_kernel(
    const float* __restrict__ qkv, const float* __restrict__ mask,
    const float* __restrict__ pad,
    unsigned short* __restrict__ oahi, unsigned short* __restrict__ oalo,
    float* __restrict__ attn_w)
{
    __shared__ float sc[2][Hh][SCP];
    __shared__ float part[4][2][Hh][68];
    __shared__ float rrs[16];
    const int tid  = threadIdx.x;
    const int lane = tid & 63;
    const int wv   = tid >> 6;
    const int si   = lane >> 3;
    const int dq   = lane & 7;
    const int b    = blockIdx.x >> 7;
    const int t0   = (blockIdx.x & 127) * 2;

    float4 qr[2][Hh][2];
    {
        const float* qb = qkv + (size_t)(b * Tt + t0) * E3 + dq * 8;
        #pragma unroll
        for (int t = 0; t < 2; ++t)
            #pragma unroll
            for (int h = 0; h < Hh; ++h) {
                qr[t][h][0] = *(const float4*)(qb + (size_t)t * E3 + h * 64);
                qr[t][h][1] = *(const float4*)(qb + (size_t)t * E3 + h * 64 + 4);
            }
    }
    const float scale = 0.125f;

    const float* mbase0 = mask + (size_t)(b * Tt + t0) * Tt * Dd + dq * 8;
    const float* mbase1 = mbase0 + (size_t)Tt * Dd;
    float4 mc[2][4];
    {
        const int s0 = wv * 32 + si;
        const float* m0p = mbase0 + (size_t)s0 * Dd;
        const float* m1p = mbase1 + (size_t)s0 * Dd;
        mc[0][0] = ntload4(m0p); mc[0][1] = ntload4(m0p + 4);
        mc[0][2] = ntload4(m1p); mc[0][3] = ntload4(m1p + 4);
    }
    #pragma unroll
    for (int c = 0; c < 4; ++c) {
        const int s = wv * 32 + c * 8 + si;
        const int cb = c & 1, nbm = cb ^ 1;
        if (c < 3) {
            const int sn = s + 8;
            const float* m0p = mbase0 + (size_t)sn * Dd;
            const float* m1p = mbase1 + (size_t)sn * Dd;
            mc[nbm][0] = ntload4(m0p); mc[nbm][1] = ntload4(m0p + 4);
            mc[nbm][2] = ntload4(m1p); mc[nbm][3] = ntload4(m1p + 4);
        }
        const float4 ma0 = mc[cb][0], mb0 = mc[cb][1];
        const float4 ma1 = mc[cb][2], mb1 = mc[cb][3];
        const float* krow = qkv + (size_t)(b * Tt + s) * E3 + Ee + dq * 8;
        const float padv = pad[b * Tt + s];
        float4 kc[2][2];
        kc[0][0] = *(const float4*)(krow);
        kc[0][1] = *(const float4*)(krow + 4);
        #pragma unroll
        for (int h = 0; h < Hh; ++h) {
            const int hb = h & 1, hn = hb ^ 1;
            if (h < 7) {
                kc[hn][0] = *(const float4*)(krow + (h + 1) * 64);
                kc[hn][1] = *(const float4*)(krow + (h + 1) * 64 + 4);
            }
            const float4 ka = kc[hb][0], kb = kc[hb][1];
            const float4 qa0 = qr[0][h][0], qb0 = qr[0][h][1];
            const float4 qa1 = qr[1][h][0], qb1 = qr[1][h][1];
            float u0 = qa0.x * ka.x + qa0.y * ka.y;
            float w0 = qa0.y * ka.x - qa0.x * ka.y;
            float u1 = qa0.z * ka.z + qa0.w * ka.w;
            float w1 = qa0.w * ka.z - qa0.z * ka.w;
            float u2 = qb0.x * kb.x + qb0.y * kb.y;
            float w2 = qb0.y * kb.x - qb0.x * kb.y;
            float u3 = qb0.z * kb.z + qb0.w * kb.w;
            float w3 = qb0.w * kb.z - qb0.z * kb.w;
            float v0 = u0 * ma0.x + w0 * ma0.y + u1 * ma0.z + w1 * ma0.w
                     + u2 * mb0.x + w2 * mb0.y + u3 * mb0.z + w3 * mb0.w;
            float s0 = qa1.x * ka.x + qa1.y * ka.y;
            float r0 = qa1.y * ka.x - qa1.x * ka.y;
            float s1 = qa1.z * ka.z + qa1.w * ka.w;
            float r1 = qa1.w * ka.z - qa1.z * ka.w;
            float s2 = qb1.x * kb.x + qb1.y * kb.y;
            float r2 = qb1.y * kb.x - qb1.x * kb.y;
            float s3 = qb1.z * kb.z + qb1.w * kb.w;
            float r3 = qb1.w * kb.z - qb1.z * kb.w;
            float v1 = s0 * ma1.x + r0 * ma1.y + s1 * ma1.z + r1 * ma1.w
                     + s2 * mb1.x + r2 * mb1.y + s3 * mb1.z + r3 * mb1.w;
            v0 = dpp_addf<0xB1>(v0); v0 = dpp_addf<0x4E>(v0); v0 = swz4_addf(v0);
            v1 = dpp_addf<0xB1>(v1); v1 = dpp_addf<0x4E>(v1); v1 = swz4_addf(v1);
            if (dq == 0) {
                sc[0][h][s] = v0 * scale + padv;
                sc[1][h][s] = v1 * scale + padv;
            }
        }
    }
    __syncthreads();

    #pragma unroll
    for (int r = 0; r < 2; ++r) {
        const int row = wv * 2 + r;
        float* pr = &sc[0][0][0] + row * SCP;
        float4 xv = *(const float4*)&pr[lane * 4];
        float mx = fmaxf(fmaxf(xv.x, xv.y), fmaxf(xv.z, xv.w));
        #pragma unroll
        for (int dlt = 32; dlt >= 1; dlt >>= 1) mx = fmaxf(mx, __shfl_xor(mx, dlt));
        float4 ev;
        ev.x = __expf(xv.x - mx);
        ev.y = __expf(xv.y - mx);
        ev.z = __expf(xv.z - mx);
        ev.w = __expf(xv.w - mx);
        float sum = (ev.x + ev.y) + (ev.z + ev.w);
        #pragma unroll
        for (int dlt = 32; dlt >= 1; dlt >>= 1) sum += __shfl_xor(sum, dlt);
        *(float4*)&pr[lane * 4] = ev;
        if (lane == 0) rrs[row] = 1.0f / sum;
    }
    __syncthreads();

    {
        const int tt = tid >> 8, s2 = tid & 255;
        float aw = 0.f;
        #pragma unroll
        for (int h = 0; h < Hh; ++h) aw += sc[tt][h][s2] * rrs[tt * 8 + h];
        attn_w[(size_t)(b * Tt + t0 + tt) * Tt + s2] = aw * 0.125f;
    }

    {
        const int sh = tid >> 7;
        const int h  = (tid >> 4) & 7;
        const int d4 = tid & 15;
        const float* vb = qkv + (size_t)b * Tt * E3 + 2 * Ee + h * 64 + d4 * 4;
        float4 o0 = make_float4(0.f, 0.f, 0.f, 0.f);
        float4 o1 = make_float4(0.f, 0.f, 0.f, 0.f);
        const int sBeg = sh * 64;
        float4 vc[2][4];
        #pragma unroll
        for (int i = 0; i < 4; ++i)
            vc[0][i] = *(const float4*)(vb + (size_t)(sBeg + i) * E3);
        #pragma unroll
        for (int it = 0; it < 16; ++it) {
            const int s2 = sBeg + it * 4;
            const int cb = it & 1, nbv = cb ^ 1;
            if (it < 15) {
                #pragma unroll
                for (int i = 0; i < 4; ++i)
                    vc[nbv][i] = *(const float4*)(vb + (size_t)(s2 + 4 + i) * E3);
            }
            const float4 p0 = *(const float4*)&sc[0][h][s2];
            const float4 p1 = *(const float4*)&sc[1][h][s2];
            const float4 va = vc[cb][0], vbv = vc[cb][1], vcv = vc[cb][2], vd = vc[cb][3];
            o0.x = fmaf(p0.x, va.x, o0.x);  o0.y = fmaf(p0.x, va.y, o0.y);
            o0.z = fmaf(p0.x, va.z, o0.z);  o0.w = fmaf(p0.x, va.w, o0.w);
            o0.x = fmaf(p0.y, vbv.x, o0.x); o0.y = fmaf(p0.y, vbv.y, o0.y);
            o0.z = fmaf(p0.y, vbv.z, o0.z); o0.w = fmaf(p0.y, vbv.w, o0.w);
            o0.x = fmaf(p0.z, vcv.x, o0.x); o0.y = fmaf(p0.z, vcv.y, o0.y);
            o0.z = fmaf(p0.z, vcv.z, o0.z); o0.w = fmaf(p0.z, vcv.w, o0.w);
            o0.x = fmaf(p0.w, vd.x, o0.x);  o0.y = fmaf(p0.w, vd.y, o0.y);
            o0.z = fmaf(p0.w, vd.z, o0.z);  o0.w = fmaf(p0.w, vd.w, o0.w);
            o1.x = fmaf(p1.x, va.x, o1.x);  o1.y = fmaf(p1.x, va.y, o1.y);
            o1.z = fmaf(p1.x, va.z, o1.z);  o1.w = fmaf(p1.x, va.w, o1.w);
            o1.x = fmaf(p1.y, vbv.x, o1.x); o1.y = fmaf(p1.y, vbv.y, o1.y);
            o1.z = fmaf(p1.y, vbv.z, o1.z); o1.w = fmaf(p1.y, vbv.w, o1.w);
            o1.x = fmaf(p1.z, vcv.x, o1.x); o1.y = fmaf(p1.z, vcv.y, o1.y);
            o1.z = fmaf(p1.z, vcv.z, o1.z); o1.w = fmaf(p1.z, vcv.w, o1.w);
            o1.x = fmaf(p1.w, vd.x, o1.x);  o1.y = fmaf(p1.w, vd.y, o1.y);
            o1.z = fmaf(p1.w, vd.z, o1.z);  o1.w = fmaf(p1.w, vd.w, o1.w);
        }
        *(float4*)&part[sh][0][h][d4 * 4] = o0;
        *(float4*)&part[sh][1][h][d4 * 4] = o1;
    }
    __syncthreads();

    {
        const int t  = tid >> 8;
        const int n2 = tid & 255;
        const int h  = n2 >> 5;
        const int dc = (2 * n2) & 63;
        const float rr = rrs[t * 8 + h];
        float ax = 0.f, ay = 0.f;
        #pragma unroll
        for (int s = 0; s < 4; ++s) {
            const float2 p = *(const float2*)&part[s][t][h][dc];
            ax += p.x; ay += p.y;
        }
        const float ox = ax * rr, oy = ay * rr;
        const unsigned short hx = bf16rne(ox), hy = bf16rne(oy);
        const unsigned short lx = bf16rne(ox - bf16tof(hx));
        const unsigned short ly = bf16rne(oy - bf16tof(hy));
        const size_t off = (size_t)(b * Tt + t0 + t) * Ee + 2 * n2;
        *(unsigned*)&oahi[off] = (unsigned)hx | ((unsigned)hy << 16);
        *(unsigned*)&oalo[off] = (unsigned)lx | ((unsigned)ly << 16);
    }
}

extern "C" void kernel_launch(void* const* d_in, const int* in_sizes, int n_in,
                              void* d_out, int out_size, void* d_ws, size_t ws_size,
                              hipStream_t stream) {
    const float* x    = (const float*)d_in[0];
    const float* mask = (const float*)d_in[1];
    const float* pad  = (const float*)d_in[2];
    const float* Wqkv = (const float*)d_in[3];
    const float* bqkv = (const float*)d_in[4];
    const float* Wo   = (const float*)d_in[5];
    const float* bo   = (const float*)d_in[6];

    float* out = (float*)d_out;

    unsigned short* Wohi = (unsigned short*)d_ws;   // 512*512
    unsigned short* Wolo = Wohi + 262144;
    unsigned short* oahi = Wolo + 262144;           // 512*512
    unsigned short* oalo = oahi + 262144;
    float* qkv = (float*)(oalo + 262144);           // B*T*3E fp32

    // qkv GEMM (768 blocks) + Wo transpose/split (64 blocks) in one launch
    mfma_qkv2<<<832, 256, 0, stream>>>(x, Wqkv, bqkv, qkv, Wo, Wohi, Wolo);

    // fused rotary scores + softmax + attn_weights + PV
    attn_kernel<<<dim3(Bb * (Tt / 2)), 512, 0, stream>>>(
        qkv, mask, pad, oahi, oalo, out + (size_t)Bb * Tt * Ee);

    // out = oa @ Wo^T + bo   (16x16 tiles split-K: grid 32 x 32 = 1024 blocks)
    mfma_proj16<<<dim3(Ee / 16, (Bb * Tt) / 16), 256, 0, stream>>>(
        oahi, oalo, Wohi, Wolo, bo, out, Bb * Tt, Ee);
}

// Round 21
// 46.634 us; speedup vs baseline: 1.0717x; 1.0717x over previous
//
#include <hip/hip_runtime.h>
#include <math.h>

#define Bb 2
#define Tt 256
#define Ee 512
#define Hh 8
#define Dd 64
#define E3 1536
#define SCP 260

typedef float vfloat4 __attribute__((ext_vector_type(4)));
typedef short bf16x8 __attribute__((ext_vector_type(8)));
typedef float f32x4 __attribute__((ext_vector_type(4)));

__device__ inline float4 ntload4(const float* p) {
    vfloat4 v = __builtin_nontemporal_load((const vfloat4*)p);
    return make_float4(v.x, v.y, v.z, v.w);
}
template<int CTRL>
__device__ inline float dpp_addf(float v) {
    int x = __builtin_amdgcn_update_dpp(0, __float_as_int(v), CTRL, 0xF, 0xF, true);
    return v + __int_as_float(x);
}
__device__ inline float swz4_addf(float v) {
    int x = __builtin_amdgcn_ds_swizzle(__float_as_int(v), 0x101F);
    return v + __int_as_float(x);
}
__device__ inline unsigned short bf16rne(float f) {
    unsigned u = __float_as_uint(f);
    return (unsigned short)((u + 0x7FFFu + ((u >> 16) & 1u)) >> 16);
}
__device__ inline float bf16tof(unsigned short h) {
    return __uint_as_float(((unsigned)h) << 16);
}
__device__ inline bf16x8 ldb(const unsigned short* p) {
    return *(const bf16x8*)(const void*)p;
}
__device__ __forceinline__ void split8(const float* p, bf16x8& hi, bf16x8& lo) {
    const float4 a = *(const float4*)p, b = *(const float4*)(p + 4);
    float f[8] = {a.x, a.y, a.z, a.w, b.x, b.y, b.z, b.w};
    bf16x8 h, l;
    #pragma unroll
    for (int i = 0; i < 8; ++i) {
        const unsigned short hh = bf16rne(f[i]);
        h[i] = (short)hh;
        l[i] = (short)bf16rne(f[i] - bf16tof(hh));
    }
    hi = h; lo = l;
}
__device__ __forceinline__ void split8a(const float* f, bf16x8& hi, bf16x8& lo) {
    bf16x8 h, l;
    #pragma unroll
    for (int i = 0; i < 8; ++i) {
        const unsigned short hh = bf16rne(f[i]);
        h[i] = (short)hh;
        l[i] = (short)bf16rne(f[i] - bf16tof(hh));
    }
    hi = h; lo = l;
}
__device__ __forceinline__ f32x4 mfma3(f32x4 acc, bf16x8 ah, bf16x8 al,
                                       bf16x8 bh, bf16x8 bl) {
    acc = __builtin_amdgcn_mfma_f32_16x16x32_bf16(ah, bh, acc, 0, 0, 0);
    acc = __builtin_amdgcn_mfma_f32_16x16x32_bf16(al, bh, acc, 0, 0, 0);
    acc = __builtin_amdgcn_mfma_f32_16x16x32_bf16(ah, bl, acc, 0, 0, 0);
    return acc;
}

// Kernel 1: blocks 0..767 = qkv GEMM (split-K MFMA, B loaded DIRECTLY from
// row-major Wqkv via strided scalar loads + on-the-fly split — no Wq prep);
// blocks 768..831 = transpose+split Wo for the later proj GEMM.
__global__ __launch_bounds__(256) void mfma_qkv2(
    const float* __restrict__ x, const float* __restrict__ Wqkv,
    const float* __restrict__ bias, float* __restrict__ C,
    const float* __restrict__ Wo,
    unsigned short* __restrict__ Wohi, unsigned short* __restrict__ Wolo)
{
    const int bid = blockIdx.x;
    const int tid = threadIdx.x;

    if (bid >= 768) {
        // ---- prep Wo tile (64 blocks) ----
        __shared__ float tile[64][65];
        const int b2 = bid - 768;
        const int kt = b2 & 7, nt = b2 >> 3;
        const int rr = tid >> 2, cc = (tid & 3) * 16;
        #pragma unroll
        for (int j = 0; j < 4; ++j) {
            const float4 v = *(const float4*)&Wo[(size_t)(kt * 64 + rr) * 512 + nt * 64 + cc + j * 4];
            tile[rr][cc + j * 4 + 0] = v.x;
            tile[rr][cc + j * 4 + 1] = v.y;
            tile[rr][cc + j * 4 + 2] = v.z;
            tile[rr][cc + j * 4 + 3] = v.w;
        }
        __syncthreads();
        unsigned short hb[16], lb[16];
        #pragma unroll
        for (int j = 0; j < 16; ++j) {
            const float f = tile[cc + j][rr];
            const unsigned short h = bf16rne(f);
            hb[j] = h;
            lb[j] = bf16rne(f - bf16tof(h));
        }
        const size_t off = (size_t)(nt * 64 + rr) * 512 + kt * 64 + cc;
        *(uint4*)&Wohi[off]     = *(const uint4*)&hb[0];
        *(uint4*)&Wohi[off + 8] = *(const uint4*)&hb[8];
        *(uint4*)&Wolo[off]     = *(const uint4*)&lb[0];
        *(uint4*)&Wolo[off + 8] = *(const uint4*)&lb[8];
        return;
    }

    // ---- qkv GEMM: 32x32 tile, 4 waves, split-K (wave owns K/4 = 128) ----
    __shared__ f32x4 red[4][2][2][64];
    const int lane = tid & 63;
    const int wv   = tid >> 6;
    const int n0   = (bid % 48) * 32;
    const int m0   = (bid / 48) * 32;
    const int fr   = lane & 15;
    const int kg   = (lane >> 4) * 8;

    f32x4 acc00 = {0.f, 0.f, 0.f, 0.f}, acc01 = acc00, acc10 = acc00, acc11 = acc00;

    #pragma unroll
    for (int s = 0; s < 4; ++s) {
        const int k0 = wv * 128 + s * 32 + kg;
        bf16x8 ah0, al0, ah1, al1;
        split8(&x[(size_t)(m0 + fr) * 512 + k0], ah0, al0);
        split8(&x[(size_t)(m0 + 16 + fr) * 512 + k0], ah1, al1);
        // B columns n0+fr, n0+16+fr of Wqkv [512][1536]
        float b0[8], b1[8];
        #pragma unroll
        for (int j = 0; j < 8; ++j) {
            b0[j] = Wqkv[(size_t)(k0 + j) * E3 + n0 + fr];
            b1[j] = Wqkv[(size_t)(k0 + j) * E3 + n0 + 16 + fr];
        }
        bf16x8 bh0, bl0, bh1, bl1;
        split8a(b0, bh0, bl0);
        split8a(b1, bh1, bl1);
        acc00 = mfma3(acc00, ah0, al0, bh0, bl0);
        acc01 = mfma3(acc01, ah0, al0, bh1, bl1);
        acc10 = mfma3(acc10, ah1, al1, bh0, bl0);
        acc11 = mfma3(acc11, ah1, al1, bh1, bl1);
    }
    red[wv][0][0][lane] = acc00;
    red[wv][0][1][lane] = acc01;
    red[wv][1][0][lane] = acc10;
    red[wv][1][1][lane] = acc11;
    __syncthreads();

    const int fi = wv >> 1, fj = wv & 1;
    f32x4 s0 = red[0][fi][fj][lane];
    const f32x4 s1 = red[1][fi][fj][lane];
    const f32x4 s2 = red[2][fi][fj][lane];
    const f32x4 s3 = red[3][fi][fj][lane];
    #pragma unroll
    for (int g = 0; g < 4; ++g) s0[g] = (s0[g] + s1[g]) + (s2[g] + s3[g]);
    const int dr = (lane >> 4) * 4, dc = lane & 15;
    const float bs = bias[n0 + fj * 16 + dc];
    #pragma unroll
    for (int g = 0; g < 4; ++g)
        C[(size_t)(m0 + fi * 16 + dr + g) * E3 + n0 + fj * 16 + dc] = s0[g] + bs;
}

// out = oa @ Wo^T + bo, split-K MFMA (r15-proven structure).
__global__ __launch_bounds__(256) void mfma_proj(
    const unsigned short* __restrict__ Ahi, const unsigned short* __restrict__ Alo,
    const unsigned short* __restrict__ Bhi, const unsigned short* __restrict__ Blo,
    const float* __restrict__ bias, float* __restrict__ C, int M, int N)
{
    __shared__ f32x4 red[4][2][2][64];
    const int lane = threadIdx.x & 63;
    const int wv   = threadIdx.x >> 6;
    const int m0   = blockIdx.y * 32;
    const int n0   = blockIdx.x * 32;
    const int fr   = lane & 15;
    const int kg   = (lane >> 4) * 8;

    f32x4 acc00 = {0.f, 0.f, 0.f, 0.f}, acc01 = acc00, acc10 = acc00, acc11 = acc00;

    #pragma unroll
    for (int s = 0; s < 4; ++s) {
        const int k0 = wv * 128 + s * 32 + kg;
        const bf16x8 ah0 = ldb(Ahi + (size_t)(m0 + fr) * 512 + k0);
        const bf16x8 al0 = ldb(Alo + (size_t)(m0 + fr) * 512 + k0);
        const bf16x8 ah1 = ldb(Ahi + (size_t)(m0 + 16 + fr) * 512 + k0);
        const bf16x8 al1 = ldb(Alo + (size_t)(m0 + 16 + fr) * 512 + k0);
        const bf16x8 bh0 = ldb(Bhi + (size_t)(n0 + fr) * 512 + k0);
        const bf16x8 bl0 = ldb(Blo + (size_t)(n0 + fr) * 512 + k0);
        const bf16x8 bh1 = ldb(Bhi + (size_t)(n0 + 16 + fr) * 512 + k0);
        const bf16x8 bl1 = ldb(Blo + (size_t)(n0 + 16 + fr) * 512 + k0);
        acc00 = mfma3(acc00, ah0, al0, bh0, bl0);
        acc01 = mfma3(acc01, ah0, al0, bh1, bl1);
        acc10 = mfma3(acc10, ah1, al1, bh0, bl0);
        acc11 = mfma3(acc11, ah1, al1, bh1, bl1);
    }
    red[wv][0][0][lane] = acc00;
    red[wv][0][1][lane] = acc01;
    red[wv][1][0][lane] = acc10;
    red[wv][1][1][lane] = acc11;
    __syncthreads();

    const int fi = wv >> 1, fj = wv & 1;
    f32x4 s0 = red[0][fi][fj][lane];
    const f32x4 s1 = red[1][fi][fj][lane];
    const f32x4 s2 = red[2][fi][fj][lane];
    const f32x4 s3 = red[3][fi][fj][lane];
    #pragma unroll
    for (int g = 0; g < 4; ++g) s0[g] = (s0[g] + s1[g]) + (s2[g] + s3[g]);
    const int dr = (lane >> 4) * 4, dc = lane & 15;
    const float bs = bias[n0 + fj * 16 + dc];
    #pragma unroll
    for (int g = 0; g < 4; ++g)
        C[(size_t)(m0 + fi * 16 + dr + g) * N + n0 + fj * 16 + dc] = s0[g] + bs;
}

// attn (r9 core, <=8.8us measured): q in VGPRs; mask/k/v ping-pong; DPP
// reduce; tail writes oa as bf16 hi/lo (r13-verified).
__global__ __launch_bounds__(512, 2) void attn_kernel(
    const float* __restrict__ qkv, const float* __restrict__ mask,
    const float* __restrict__ pad,
    unsigned short* __restrict__ oahi, unsigned short* __restrict__ oalo,
    float* __restrict__ attn_w)
{
    __shared__ float sc[2][Hh][SCP];
    __shared__ float part[4][2][Hh][68];
    __shared__ float rrs[16];
    const int tid  = threadIdx.x;
    const int lane = tid & 63;
    const int wv   = tid >> 6;
    const int si   = lane >> 3;
    const int dq   = lane & 7;
    const int b    = blockIdx.x >> 7;
    const int t0   = (blockIdx.x & 127) * 2;

    float4 qr[2][Hh][2];
    {
        const float* qb = qkv + (size_t)(b * Tt + t0) * E3 + dq * 8;
        #pragma unroll
        for (int t = 0; t < 2; ++t)
            #pragma unroll
            for (int h = 0; h < Hh; ++h) {
                qr[t][h][0] = *(const float4*)(qb + (size_t)t * E3 + h * 64);
                qr[t][h][1] = *(const float4*)(qb + (size_t)t * E3 + h * 64 + 4);
            }
    }
    const float scale = 0.125f;

    const float* mbase0 = mask + (size_t)(b * Tt + t0) * Tt * Dd + dq * 8;
    const float* mbase1 = mbase0 + (size_t)Tt * Dd;
    float4 mc[2][4];
    {
        const int s0 = wv * 32 + si;
        const float* m0p = mbase0 + (size_t)s0 * Dd;
        const float* m1p = mbase1 + (size_t)s0 * Dd;
        mc[0][0] = ntload4(m0p); mc[0][1] = ntload4(m0p + 4);
        mc[0][2] = ntload4(m1p); mc[0][3] = ntload4(m1p + 4);
    }
    #pragma unroll
    for (int c = 0; c < 4; ++c) {
        const int s = wv * 32 + c * 8 + si;
        const int cb = c & 1, nbm = cb ^ 1;
        if (c < 3) {
            const int sn = s + 8;
            const float* m0p = mbase0 + (size_t)sn * Dd;
            const float* m1p = mbase1 + (size_t)sn * Dd;
            mc[nbm][0] = ntload4(m0p); mc[nbm][1] = ntload4(m0p + 4);
            mc[nbm][2] = ntload4(m1p); mc[nbm][3] = ntload4(m1p + 4);
        }
        const float4 ma0 = mc[cb][0], mb0 = mc[cb][1];
        const float4 ma1 = mc[cb][2], mb1 = mc[cb][3];
        const float* krow = qkv + (size_t)(b * Tt + s) * E3 + Ee + dq * 8;
        const float padv = pad[b * Tt + s];
        float4 kc[2][2];
        kc[0][0] = *(const float4*)(krow);
        kc[0][1] = *(const float4*)(krow + 4);
        #pragma unroll
        for (int h = 0; h < Hh; ++h) {
            const int hb = h & 1, hn = hb ^ 1;
            if (h < 7) {
                kc[hn][0] = *(const float4*)(krow + (h + 1) * 64);
                kc[hn][1] = *(const float4*)(krow + (h + 1) * 64 + 4);
            }
            const float4 ka = kc[hb][0], kb = kc[hb][1];
            const float4 qa0 = qr[0][h][0], qb0 = qr[0][h][1];
            const float4 qa1 = qr[1][h][0], qb1 = qr[1][h][1];
            float u0 = qa0.x * ka.x + qa0.y * ka.y;
            float w0 = qa0.y * ka.x - qa0.x * ka.y;
            float u1 = qa0.z * ka.z + qa0.w * ka.w;
            float w1 = qa0.w * ka.z - qa0.z * ka.w;
            float u2 = qb0.x * kb.x + qb0.y * kb.y;
            float w2 = qb0.y * kb.x - qb0.x * kb.y;
            float u3 = qb0.z * kb.z + qb0.w * kb.w;
            float w3 = qb0.w * kb.z - qb0.z * kb.w;
            float v0 = u0 * ma0.x + w0 * ma0.y + u1 * ma0.z + w1 * ma0.w
                     + u2 * mb0.x + w2 * mb0.y + u3 * mb0.z + w3 * mb0.w;
            float s0 = qa1.x * ka.x + qa1.y * ka.y;
            float r0 = qa1.y * ka.x - qa1.x * ka.y;
            float s1 = qa1.z * ka.z + qa1.w * ka.w;
            float r1 = qa1.w * ka.z - qa1.z * ka.w;
            float s2 = qb1.x * kb.x + qb1.y * kb.y;
            float r2 = qb1.y * kb.x - qb1.x * kb.y;
            float s3 = qb1.z * kb.z + qb1.w * kb.w;
            float r3 = qb1.w * kb.z - qb1.z * kb.w;
            float v1 = s0 * ma1.x + r0 * ma1.y + s1 * ma1.z + r1 * ma1.w
                     + s2 * mb1.x + r2 * mb1.y + s3 * mb1.z + r3 * mb1.w;
            v0 = dpp_addf<0xB1>(v0); v0 = dpp_addf<0x4E>(v0); v0 = swz4_addf(v0);
            v1 = dpp_addf<0xB1>(v1); v1 = dpp_addf<0x4E>(v1); v1 = swz4_addf(v1);
            if (dq == 0) {
                sc[0][h][s] = v0 * scale + padv;
                sc[1][h][s] = v1 * scale + padv;
            }
        }
    }
    __syncthreads();

    #pragma unroll
    for (int r = 0; r < 2; ++r) {
        const int row = wv * 2 + r;
        float* pr = &sc[0][0][0] + row * SCP;
        float4 xv = *(const float4*)&pr[lane * 4];
        float mx = fmaxf(fmaxf(xv.x, xv.y), fmaxf(xv.z, xv.w));
        #pragma unroll
        for (int dlt = 32; dlt >= 1; dlt >>= 1) mx = fmaxf(mx, __shfl_xor(mx, dlt));
        float4 ev;
        ev.x = __expf(xv.x - mx);
        ev.y = __expf(xv.y - mx);
        ev.z = __expf(xv.z - mx);
        ev.w = __expf(xv.w - mx);
        float sum = (ev.x + ev.y) + (ev.z + ev.w);
        #pragma unroll
        for (int dlt = 32; dlt >= 1; dlt >>= 1) sum += __shfl_xor(sum, dlt);
        *(float4*)&pr[lane * 4] = ev;
        if (lane == 0) rrs[row] = 1.0f / sum;
    }
    __syncthreads();

    {
        const int tt = tid >> 8, s2 = tid & 255;
        float aw = 0.f;
        #pragma unroll
        for (int h = 0; h < Hh; ++h) aw += sc[tt][h][s2] * rrs[tt * 8 + h];
        attn_w[(size_t)(b * Tt + t0 + tt) * Tt + s2] = aw * 0.125f;
    }

    {
        const int sh = tid >> 7;
        const int h  = (tid >> 4) & 7;
        const int d4 = tid & 15;
        const float* vb = qkv + (size_t)b * Tt * E3 + 2 * Ee + h * 64 + d4 * 4;
        float4 o0 = make_float4(0.f, 0.f, 0.f, 0.f);
        float4 o1 = make_float4(0.f, 0.f, 0.f, 0.f);
        const int sBeg = sh * 64;
        float4 vc[2][4];
        #pragma unroll
        for (int i = 0; i < 4; ++i)
            vc[0][i] = *(const float4*)(vb + (size_t)(sBeg + i) * E3);
        #pragma unroll
        for (int it = 0; it < 16; ++it) {
            const int s2 = sBeg + it * 4;
            const int cb = it & 1, nbv = cb ^ 1;
            if (it < 15) {
                #pragma unroll
                for (int i = 0; i < 4; ++i)
                    vc[nbv][i] = *(const float4*)(vb + (size_t)(s2 + 4 + i) * E3);
            }
            const float4 p0 = *(const float4*)&sc[0][h][s2];
            const float4 p1 = *(const float4*)&sc[1][h][s2];
            const float4 va = vc[cb][0], vbv = vc[cb][1], vcv = vc[cb][2], vd = vc[cb][3];
            o0.x = fmaf(p0.x, va.x, o0.x);  o0.y = fmaf(p0.x, va.y, o0.y);
            o0.z = fmaf(p0.x, va.z, o0.z);  o0.w = fmaf(p0.x, va.w, o0.w);
            o0.x = fmaf(p0.y, vbv.x, o0.x); o0.y = fmaf(p0.y, vbv.y, o0.y);
            o0.z = fmaf(p0.y, vbv.z, o0.z); o0.w = fmaf(p0.y, vbv.w, o0.w);
            o0.x = fmaf(p0.z, vcv.x, o0.x); o0.y = fmaf(p0.z, vcv.y, o0.y);
            o0.z = fmaf(p0.z, vcv.z, o0.z); o0.w = fmaf(p0.z, vcv.w, o0.w);
            o0.x = fmaf(p0.w, vd.x, o0.x);  o0.y = fmaf(p0.w, vd.y, o0.y);
            o0.z = fmaf(p0.w, vd.z, o0.z);  o0.w = fmaf(p0.w, vd.w, o0.w);
            o1.x = fmaf(p1.x, va.x, o1.x);  o1.y = fmaf(p1.x, va.y, o1.y);
            o1.z = fmaf(p1.x, va.z, o1.z);  o1.w = fmaf(p1.x, va.w, o1.w);
            o1.x = fmaf(p1.y, vbv.x, o1.x); o1.y = fmaf(p1.y, vbv.y, o1.y);
            o1.z = fmaf(p1.y, vbv.z, o1.z); o1.w = fmaf(p1.y, vbv.w, o1.w);
            o1.x = fmaf(p1.z, vcv.x, o1.x); o1.y = fmaf(p1.z, vcv.y, o1.y);
            o1.z = fmaf(p1.z, vcv.z, o1.z); o1.w = fmaf(p1.z, vcv.w, o1.w);
            o1.x = fmaf(p1.w, vd.x, o1.x);  o1.y = fmaf(p1.w, vd.y, o1.y);
            o1.z = fmaf(p1.w, vd.z, o1.z);  o1.w = fmaf(p1.w, vd.w, o1.w);
        }
        *(float4*)&part[sh][0][h][d4 * 4] = o0;
        *(float4*)&part[sh][1][h][d4 * 4] = o1;
    }
    __syncthreads();

    {
        const int t  = tid >> 8;
        const int n2 = tid & 255;
        const int h  = n2 >> 5;
        const int dc = (2 * n2) & 63;
        const float rr = rrs[t * 8 + h];
        float ax = 0.f, ay = 0.f;
        #pragma unroll
        for (int s = 0; s < 4; ++s) {
            const float2 p = *(const float2*)&part[s][t][h][dc];
            ax += p.x; ay += p.y;
        }
        const float ox = ax * rr, oy = ay * rr;
        const unsigned short hx = bf16rne(ox), hy = bf16rne(oy);
        const unsigned short lx = bf16rne(ox - bf16tof(hx));
        const unsigned short ly = bf16rne(oy - bf16tof(hy));
        const size_t off = (size_t)(b * Tt + t0 + t) * Ee + 2 * n2;
        *(unsigned*)&oahi[off] = (unsigned)hx | ((unsigned)hy << 16);
        *(unsigned*)&oalo[off] = (unsigned)lx | ((unsigned)ly << 16);
    }
}

extern "C" void kernel_launch(void* const* d_in, const int* in_sizes, int n_in,
                              void* d_out, int out_size, void* d_ws, size_t ws_size,
                              hipStream_t stream) {
    const float* x    = (const float*)d_in[0];
    const float* mask = (const float*)d_in[1];
    const float* pad  = (const float*)d_in[2];
    const float* Wqkv = (const float*)d_in[3];
    const float* bqkv = (const float*)d_in[4];
    const float* Wo   = (const float*)d_in[5];
    const float* bo   = (const float*)d_in[6];

    float* out = (float*)d_out;

    unsigned short* Wohi = (unsigned short*)d_ws;   // 512*512
    unsigned short* Wolo = Wohi + 262144;
    unsigned short* oahi = Wolo + 262144;           // 512*512
    unsigned short* oalo = oahi + 262144;
    float* qkv = (float*)(oalo + 262144);           // B*T*3E fp32

    // qkv GEMM (768 blocks) + Wo transpose/split (64 blocks) in one launch
    mfma_qkv2<<<832, 256, 0, stream>>>(x, Wqkv, bqkv, qkv, Wo, Wohi, Wolo);

    // fused rotary scores + softmax + attn_weights + PV
    attn_kernel<<<dim3(Bb * (Tt / 2)), 512, 0, stream>>>(
        qkv, mask, pad, oahi, oalo, out + (size_t)Bb * Tt * Ee);

    // out = oa @ Wo^T + bo   (split-K MFMA: grid 16 x 16 = 256 blocks)
    mfma_proj<<<dim3(Ee / 32, (Bb * Tt) / 32), 256, 0, stream>>>(
        oahi, oalo, Wohi, Wolo, bo, out, Bb * Tt, Ee);
}